// Round 14
// baseline (165.894 us; speedup 1.0000x reference)
//
#include <hip/hip_runtime.h>
#include <math.h>

#define Bsz 4
#define Nseq 2048
#define Cdim 512
#define Hn 8
#define Dh 64
#define TK 256
#define BH (Bsz*Hn)          // 32
#define QKVC 1536

typedef __attribute__((ext_vector_type(8))) short bf16x8;
typedef __attribute__((ext_vector_type(4))) float f32x4;

__device__ __forceinline__ unsigned short f2bf(float x) {
    unsigned u = __float_as_uint(x);
    unsigned r = (u + 0x7fffu + ((u >> 16) & 1u)) >> 16;   // round-to-nearest-even
    return (unsigned short)r;
}
__device__ __forceinline__ float bf2f(unsigned short h) {
    return __uint_as_float((unsigned)h << 16);
}
__device__ __forceinline__ f32x4 mfma16(bf16x8 a, bf16x8 b, f32x4 c) {
    return __builtin_amdgcn_mfma_f32_16x16x32_bf16(a, b, c, 0, 0, 0);
}

// ---------------------------------------------------------------
// statsAW: block-range fusion; xprep FOLDED IN (column sums read
// directly from x with the bit-identical reduction tree:
// 16-row chunk sums in row order, then 16 chunks in order).
//  blocks [0,384):   statsA partial stats GEMM (b=u&3, kc=(u>>2)&15, nb=u>>6)
//  blocks [384,768): W-pack w_qkv -> hi/lo bf16 fragments
// ---------------------------------------------------------------
__global__ __launch_bounds__(256) void statsAW(const float* __restrict__ x,
                                               const float* __restrict__ w_qkv,
                                               float* __restrict__ spart,
                                               bf16x8* __restrict__ hi,
                                               bf16x8* __restrict__ lo) {
    int bid = blockIdx.x;
    int t = threadIdx.x;
    if (bid < 384) {
        int b = bid & 3, kc = (bid >> 2) & 15, nb = bid >> 6;
        __shared__ float xr[8][32];
        __shared__ float xs[32];
        int i = t & 31, g = t >> 5;
        // rows g*256 .. g*256+255 of column kc*32+i, chunked 16x16.
        // Tree identical to old xprep(16-row chunks) + statsA(16-chunk sum).
        const float* xb = x + (size_t)b * Nseq * Cdim + kc * 32 + i;
        float s = 0.f;
        #pragma unroll 4
        for (int j = 0; j < 16; ++j) {
            const float* rp = xb + (size_t)(g * 256 + j * 16) * Cdim;
            float v[16];
            #pragma unroll
            for (int rr = 0; rr < 16; ++rr) v[rr] = rp[rr * Cdim];
            float c = 0.f;
            #pragma unroll
            for (int rr = 0; rr < 16; ++rr) c += v[rr];
            s += c;
        }
        xr[g][i] = s;
        __syncthreads();
        if (t < 32) {
            float v = 0.f;
            #pragma unroll
            for (int gg = 0; gg < 8; ++gg) v += xr[gg][t];
            xs[t] = v;
        }
        __syncthreads();
        const float* wbase = w_qkv + (size_t)(kc * 32) * QKVC + nb * 256 + t;
        float wv[32];
        #pragma unroll
        for (int i2 = 0; i2 < 32; ++i2)
            wv[i2] = wbase[(size_t)i2 * QKVC];
        float a0 = 0.f;
        #pragma unroll
        for (int i2 = 0; i2 < 32; ++i2)
            a0 += xs[i2] * wv[i2];
        spart[(size_t)(b * 16 + kc) * QKVC + nb * 256 + t] = a0;
    } else {
        int u = bid - 384;
        int nt = u >> 2;
        int kt = (u & 3) * 4 + (t >> 6);
        int lane = t & 63;
        int c = nt * 16 + (lane & 15);
        int kbase = kt * 32 + (lane >> 4) * 8;
        bf16x8 h, l;
        #pragma unroll
        for (int j = 0; j < 8; ++j) {
            float v = w_qkv[(size_t)(kbase + j) * QKVC + c];
            unsigned short hv = f2bf(v);
            h[j] = (short)hv;
            l[j] = (short)f2bf(v - bf2f(hv));
        }
        int idx = (nt * 16 + kt) * 64 + lane;
        hi[idx] = h;
        lo[idx] = l;
    }
}

// ---------------------------------------------------------------
// statsB: finalize qm/km/sv from spart, then rvec/cvec. grid (32, 2).
// ---------------------------------------------------------------
__global__ __launch_bounds__(256) void statsB(const float* __restrict__ spart,
                                              const float* __restrict__ w_qkv,
                                              float* __restrict__ sv,
                                              float* __restrict__ rvec,
                                              float* __restrict__ cvec) {
    int bh = blockIdx.x, cb = blockIdx.y;
    int b = bh >> 3, h = bh & 7;
    __shared__ float qm[64], km[64];
    int t = threadIdx.x;
    if (t < 192) {
        int which = t >> 6, d = t & 63;
        int col = which * 512 + h * 64 + d;
        float pv[16];
        #pragma unroll
        for (int kc = 0; kc < 16; ++kc)
            pv[kc] = spart[(size_t)(b * 16 + kc) * QKVC + col];
        float s = 0.f;
        #pragma unroll
        for (int kc = 0; kc < 16; ++kc) s += pv[kc];
        if (which == 0)      qm[d] = s * (1.0f / Nseq);
        else if (which == 1) km[d] = s * (1.0f / Nseq);
        else if (cb == 0)    sv[bh * 64 + d] = s;
    }
    __syncthreads();
    int c = cb * 256 + t;
    const float4* wr = (const float4*)(w_qkv + (size_t)c * QKVC + h * 64);
    const float4* wc = (const float4*)(w_qkv + (size_t)c * QKVC + 512 + h * 64);
    float r = 0.f, cv = 0.f;
    #pragma unroll
    for (int d4 = 0; d4 < 16; ++d4) {
        float4 w1 = wr[d4], w2 = wc[d4];
        float4 k1 = *(const float4*)&km[d4 * 4];
        float4 q1 = *(const float4*)&qm[d4 * 4];
        r  += w1.x * k1.x + w1.y * k1.y + w1.z * k1.z + w1.w * k1.w;
        cv += w2.x * q1.x + w2.y * q1.y + w2.z * q1.z + w2.w * q1.w;
    }
    rvec[(size_t)bh * Cdim + c] = r;
    cvec[(size_t)bh * Cdim + c] = cv;
}

// ---------------------------------------------------------------
// score4: single-pass rank-1 scores.  grid (4 b, 128 rc), 128 threads.
// ---------------------------------------------------------------
__global__ __launch_bounds__(128) void score4_kernel(const float* __restrict__ x,
                                                     const float* __restrict__ rvec,
                                                     const float* __restrict__ cvec,
                                                     float* __restrict__ rsc,
                                                     float* __restrict__ csc) {
    int b = blockIdx.x, rc = blockIdx.y;
    __shared__ float vs[16 * 8 * 68];     // 34.8 KB
    int t = threadIdx.x;
    int r = t >> 3, g = t & 7;

    const float4* xp = (const float4*)(x + ((size_t)b * Nseq + rc * 16 + r) * Cdim + g * 64);
    float4 xr[16];
    #pragma unroll
    for (int j4 = 0; j4 < 16; ++j4) xr[j4] = xp[j4];

    {
        const float4* rp = (const float4*)(rvec + (size_t)b * 8 * Cdim);
        const float4* cp = (const float4*)(cvec + (size_t)b * 8 * Cdim);
        for (int i = t; i < 16 * 128; i += 128) {
            int v = i >> 7, c4 = i & 127;
            float4 val = (v < 8) ? rp[v * 128 + c4] : cp[(v - 8) * 128 + c4];
            int gg = c4 >> 4, j4 = c4 & 15;
            *(float4*)&vs[(v * 8 + gg) * 68 + j4 * 4] = val;
        }
    }
    __syncthreads();

    float acc[16];
    #pragma unroll
    for (int v = 0; v < 16; ++v) acc[v] = 0.f;
    #pragma unroll
    for (int j4 = 0; j4 < 16; ++j4) {
        float4 xv = xr[j4];
        #pragma unroll
        for (int v = 0; v < 16; ++v) {
            float4 wv = *(const float4*)&vs[(v * 8 + g) * 68 + j4 * 4];
            acc[v] += xv.x * wv.x + xv.y * wv.y + xv.z * wv.z + xv.w * wv.w;
        }
    }
    #pragma unroll
    for (int v = 0; v < 16; ++v) {
        float s = acc[v];
        s += __shfl_xor(s, 1, 64);
        s += __shfl_xor(s, 2, 64);
        s += __shfl_xor(s, 4, 64);
        acc[v] = s;
    }
    if (g == 0) {
        int i = rc * 16 + r;
        #pragma unroll
        for (int v = 0; v < 8; ++v) {
            rsc[(size_t)(b * 8 + v) * Nseq + i] = acc[v] * 0.125f;
            csc[(size_t)(b * 8 + v) * Nseq + i] = acc[8 + v] * 0.125f;
        }
    }
}

// ---------------------------------------------------------------
// topk6: radix-select top-256, shfl scans + per-wave histograms.
// grid 64.  (unchanged)
// ---------------------------------------------------------------
__global__ __launch_bounds__(256) void topk6(const float* __restrict__ rsc,
                                             const float* __restrict__ csc,
                                             int* __restrict__ ridx,
                                             int* __restrict__ cidx,
                                             int* __restrict__ rankmap) {
    int selid = blockIdx.x;
    int bh = selid >> 1, which = selid & 1;
    const float* sin = which ? (csc + (size_t)bh * Nseq) : (rsc + (size_t)bh * Nseq);
    __shared__ int hist[4][256];
    __shared__ int wsum[4];
    __shared__ int tieidx[2048];
    __shared__ int sh_D, sh_above, sh_tiecnt;
    int tid = threadIdx.x;
    int lane = tid & 63, wv = tid >> 6;

    unsigned k[8];
    #pragma unroll
    for (int j = 0; j < 8; ++j) {
        unsigned u = __float_as_uint(sin[j * 256 + tid]);
        k[j] = (u & 0x80000000u) ? ~u : (u | 0x80000000u);
    }

    unsigned pref = 0;
    int above = 0;
    for (int level = 3; level >= 0; --level) {
        hist[0][tid] = 0; hist[1][tid] = 0; hist[2][tid] = 0; hist[3][tid] = 0;
        __syncthreads();
        int sh = level * 8;
        #pragma unroll
        for (int j = 0; j < 8; ++j) {
            bool match = (level == 3) || ((k[j] >> (sh + 8)) == pref);
            if (match) atomicAdd(&hist[wv][(k[j] >> sh) & 255], 1);
        }
        __syncthreads();
        int h = hist[0][tid] + hist[1][tid] + hist[2][tid] + hist[3][tid];
        int v = h;
        #pragma unroll
        for (int off = 1; off < 64; off <<= 1) {
            int tt = __shfl_down(v, off, 64);
            if (lane + off < 64) v += tt;
        }
        if (lane == 0) wsum[wv] = v;
        __syncthreads();
        int add = 0;
        #pragma unroll
        for (int w = 0; w < 4; ++w) if (w > wv) add += wsum[w];
        v += add;
        int Sincl = v, Sexcl = v - h;
        if (above + Sexcl < TK && above + Sincl >= TK) {
            sh_D = tid;
            sh_above = above + Sexcl;
        }
        __syncthreads();
        pref = (pref << 8) | (unsigned)sh_D;
        above = sh_above;
        __syncthreads();
    }
    unsigned T = pref;
    int rem = TK - above;

    if (tid == 0) sh_tiecnt = 0;
    __syncthreads();
    int cnt = 0;
    #pragma unroll
    for (int j = 0; j < 8; ++j) {
        if (k[j] > T) ++cnt;
        if (k[j] == T) {
            int p = atomicAdd(&sh_tiecnt, 1);
            tieidx[p] = j * 256 + tid;
        }
    }
    int v = cnt;
    #pragma unroll
    for (int off = 1; off < 64; off <<= 1) {
        int tt = __shfl_up(v, off, 64);
        if (lane >= off) v += tt;
    }
    if (lane == 63) wsum[wv] = v;
    __syncthreads();
    int add = 0;
    #pragma unroll
    for (int w = 0; w < 4; ++w) if (w < wv) add += wsum[w];
    int base = v + add - cnt;
    int tc = sh_tiecnt;
    int* outp = which ? (cidx + bh * TK) : (ridx + bh * TK);
    #pragma unroll
    for (int j = 0; j < 8; ++j) {
        int i = j * 256 + tid;
        int r = -1;
        if (k[j] > T) {
            r = base++;
        } else if (k[j] == T) {
            int rk = 0;
            for (int t2 = 0; t2 < tc; ++t2) rk += (tieidx[t2] < i) ? 1 : 0;
            if (rk < rem) r = above + rk;
        }
        if (r >= 0) outp[r] = i;
        if (which == 0) rankmap[(size_t)bh * Nseq + i] = r;
    }
}

// ---------------------------------------------------------------
// selgemm4: barrier-free gather-GEMM, NI=4, 1-deep B prefetch.
// grid (4 mq, 3 part, 32 bh).  (unchanged)
// ---------------------------------------------------------------
__global__ __launch_bounds__(256) void selgemm4(const float* __restrict__ x,
                                                const int* __restrict__ ridx,
                                                const int* __restrict__ cidx,
                                                const bf16x8* __restrict__ Bph,
                                                const bf16x8* __restrict__ Bpl,
                                                float* __restrict__ qsel,
                                                float* __restrict__ ksel,
                                                float* __restrict__ vsel) {
    int mq = blockIdx.x, part = blockIdx.y, bh = blockIdx.z;
    int b = bh >> 3, h = bh & 7;
    int tid = threadIdx.x;
    int wv = tid >> 6, lane = tid & 63;
    const int* idxp = (part == 0 ? ridx : cidx) + bh * TK + mq * 64 + wv * 16;
    int row = idxp[lane & 15];
    const float* ap = x + ((size_t)b * Nseq + row) * Cdim + (lane >> 4) * 8;
    size_t orow = (size_t)bh * TK + mq * 64 + wv * 16;
    int nt0 = (part == 0) ? (h * 4) : (part == 1 ? (32 + h * 4) : (64 + h * 4));
    float* outp = (part == 0) ? qsel : (part == 1 ? ksel : vsel);

    f32x4 acc[4];
    #pragma unroll
    for (int i = 0; i < 4; ++i) acc[i] = (f32x4){0.f, 0.f, 0.f, 0.f};

    bf16x8 bhc[4], blc[4];
    #pragma unroll
    for (int ni = 0; ni < 4; ++ni) {
        bhc[ni] = Bph[((size_t)(nt0 + ni) * 16 + 0) * 64 + lane];
        blc[ni] = Bpl[((size_t)(nt0 + ni) * 16 + 0) * 64 + lane];
    }
    float4 a0 = *(const float4*)ap;
    float4 a1 = *(const float4*)(ap + 4);
    #pragma unroll 2
    for (int kt = 0; kt < 16; ++kt) {
        float4 na0 = a0, na1 = a1;
        bf16x8 bhn[4], bln[4];
        if (kt < 15) {
            na0 = *(const float4*)(ap + (kt + 1) * 32);
            na1 = *(const float4*)(ap + (kt + 1) * 32 + 4);
            #pragma unroll
            for (int ni = 0; ni < 4; ++ni) {
                bhn[ni] = Bph[((size_t)(nt0 + ni) * 16 + (kt + 1)) * 64 + lane];
                bln[ni] = Bpl[((size_t)(nt0 + ni) * 16 + (kt + 1)) * 64 + lane];
            }
        }
        float vv[8] = {a0.x, a0.y, a0.z, a0.w, a1.x, a1.y, a1.z, a1.w};
        bf16x8 ah, al;
        #pragma unroll
        for (int j = 0; j < 8; ++j) {
            unsigned short hv = f2bf(vv[j]);
            ah[j] = (short)hv;
            al[j] = (short)f2bf(vv[j] - bf2f(hv));
        }
        #pragma unroll
        for (int ni = 0; ni < 4; ++ni) {
            acc[ni] = mfma16(ah, bhc[ni], acc[ni]);
            acc[ni] = mfma16(ah, blc[ni], acc[ni]);
            acc[ni] = mfma16(al, bhc[ni], acc[ni]);
        }
        if (kt < 15) {
            #pragma unroll
            for (int ni = 0; ni < 4; ++ni) { bhc[ni] = bhn[ni]; blc[ni] = bln[ni]; }
        }
        a0 = na0; a1 = na1;
    }
    int cl = lane & 15, rq = (lane >> 4) * 4;
    #pragma unroll
    for (int ni = 0; ni < 4; ++ni) {
        int csub = ni * 16 + cl;
        #pragma unroll
        for (int r = 0; r < 4; ++r)
            outp[(orow + rq + r) * 64 + csub] = acc[ni][r];
    }
}

// ---------------------------------------------------------------
// attn_fused4: grid (32 bh, 16 rblk).  (unchanged)
// ---------------------------------------------------------------
__global__ __launch_bounds__(256) void attn_fused4(const float* __restrict__ qsel,
                                                   const float* __restrict__ ksel,
                                                   const float* __restrict__ vsel,
                                                   const float* __restrict__ sv,
                                                   float* __restrict__ delta) {
    int bh = blockIdx.x;
    int rblk = blockIdx.y;
    __shared__ float Kt[64 * 256];       // 64 KB; E[16][256] aliases after QK
    __shared__ float Qs[16 * 64];        // 4 KB
    __shared__ float umS[16], izS[16];
    int tid = threadIdx.x;
    {
        int j = tid;
        const float4* kp4 = (const float4*)(ksel + ((size_t)bh * TK + j) * 64);
        float4 kv[16];
        #pragma unroll
        for (int d4 = 0; d4 < 16; ++d4) kv[d4] = kp4[d4];
        #pragma unroll
        for (int d4 = 0; d4 < 16; ++d4) {
            Kt[(d4 * 4 + 0) * 256 + j] = kv[d4].x;
            Kt[(d4 * 4 + 1) * 256 + j] = kv[d4].y;
            Kt[(d4 * 4 + 2) * 256 + j] = kv[d4].z;
            Kt[(d4 * 4 + 3) * 256 + j] = kv[d4].w;
        }
    }
    for (int idx = tid; idx < 16 * 64; idx += 256)
        Qs[idx] = qsel[((size_t)bh * TK + rblk * 16) * 64 + idx];
    __syncthreads();

    int wave = tid >> 6, lane = tid & 63;
    int iw0 = wave * 4;
    float e[4][4];
    #pragma unroll
    for (int r = 0; r < 4; ++r)
        #pragma unroll
        for (int t = 0; t < 4; ++t) e[r][t] = 0.f;
    #pragma unroll 16
    for (int d = 0; d < 64; ++d) {
        float4 kv = *(const float4*)&Kt[d * 256 + 4 * lane];
        #pragma unroll
        for (int r = 0; r < 4; ++r) {
            float qd = Qs[(iw0 + r) * 64 + d];
            e[r][0] += qd * kv.x; e[r][1] += qd * kv.y;
            e[r][2] += qd * kv.z; e[r][3] += qd * kv.w;
        }
    }
    #pragma unroll
    for (int r = 0; r < 4; ++r) {
        float s0 = e[r][0] * 0.125f, s1 = e[r][1] * 0.125f;
        float s2 = e[r][2] * 0.125f, s3 = e[r][3] * 0.125f;
        float mx = fmaxf(fmaxf(s0, s1), fmaxf(s2, s3));
        #pragma unroll
        for (int off = 32; off; off >>= 1) mx = fmaxf(mx, __shfl_xor(mx, off, 64));
        mx = fmaxf(mx, 0.0f);
        float e0 = __expf(s0 - mx), e1 = __expf(s1 - mx);
        float e2 = __expf(s2 - mx), e3 = __expf(s3 - mx);
        float zs = e0 + e1 + e2 + e3;
        #pragma unroll
        for (int off = 32; off; off >>= 1) zs += __shfl_xor(zs, off, 64);
        if (lane == 0) {
            float em = __expf(-mx);
            umS[iw0 + r] = em;
            izS[iw0 + r] = 1.0f / ((float)(Nseq - TK) * em + zs);
        }
        e[r][0] = e0; e[r][1] = e1; e[r][2] = e2; e[r][3] = e3;
    }
    __syncthreads();
    float* E = Kt;
    #pragma unroll
    for (int r = 0; r < 4; ++r)
        *(float4*)&E[(iw0 + r) * 256 + 4 * lane] = (float4){e[r][0], e[r][1], e[r][2], e[r][3]};
    __syncthreads();

    const float* vbase = vsel + (size_t)bh * TK * 64 + lane;
    float ssel = 0.f;
    float acc[4];
    #pragma unroll
    for (int r = 0; r < 4; ++r) acc[r] = 0.f;
    #pragma unroll 16
    for (int j = 0; j < TK; ++j) {
        float v = vbase[j * 64];
        ssel += v;
        #pragma unroll
        for (int r = 0; r < 4; ++r)
            acc[r] += E[(iw0 + r) * 256 + j] * v;
    }
    float svd = sv[bh * 64 + lane];
    float sadj = svd - ssel;
    float uval = svd * (1.0f / Nseq);
    #pragma unroll
    for (int r = 0; r < 4; ++r) {
        int i = rblk * 16 + iw0 + r;
        float outv = (umS[iw0 + r] * sadj + acc[r]) * izS[iw0 + r];
        delta[((size_t)bh * TK + i) * 64 + lane] = outv - uval;
    }
}

// ---------------------------------------------------------------
// deltamm_ub: 64-row tiles; register-staged LDS fills.  (unchanged)
// ---------------------------------------------------------------
__global__ __launch_bounds__(256) void deltamm_ub(const float* __restrict__ delta,
                                                  const float* __restrict__ w_out,
                                                  const float* __restrict__ b_out,
                                                  const float* __restrict__ sv,
                                                  float* __restrict__ deltaout,
                                                  float* __restrict__ ubase) {
    int bid = blockIdx.x;
    int tid = threadIdx.x;
    if (bid < 512) {
        int bh = bid >> 4, sub = bid & 15;
        int rh = sub >> 2, ct = sub & 3;
        int h = bh & 7;
        __shared__ float As[64][65];
        __shared__ float Ws[64][132];
        {
            float av[16];
            #pragma unroll
            for (int it = 0; it < 16; ++it) {
                int idx = tid + it * 256;
                int row = idx >> 6, k = idx & 63;
                av[it] = delta[((size_t)bh * TK + rh * 64 + row) * 64 + k];
            }
            float wv[32];
            #pragma unroll
            for (int it = 0; it < 32; ++it) {
                int idx = tid + it * 256;
                int k = idx >> 7, c = idx & 127;
                wv[it] = w_out[(size_t)(h * 64 + k) * 512 + ct * 128 + c];
            }
            #pragma unroll
            for (int it = 0; it < 16; ++it) {
                int idx = tid + it * 256;
                As[idx >> 6][idx & 63] = av[it];
            }
            #pragma unroll
            for (int it = 0; it < 32; ++it) {
                int idx = tid + it * 256;
                Ws[idx >> 7][idx & 127] = wv[it];
            }
        }
        __syncthreads();
        int tx = tid & 15, ty = tid >> 4;
        float acc[4][8];
        #pragma unroll
        for (int r = 0; r < 4; ++r)
            #pragma unroll
            for (int c = 0; c < 8; ++c) acc[r][c] = 0.f;
        for (int k = 0; k < 64; ++k) {
            float a[4], bv[8];
            #pragma unroll
            for (int r = 0; r < 4; ++r) a[r] = As[ty * 4 + r][k];
            #pragma unroll
            for (int cc = 0; cc < 4; ++cc) {
                bv[cc]     = Ws[k][tx * 4 + cc];
                bv[4 + cc] = Ws[k][64 + tx * 4 + cc];
            }
            #pragma unroll
            for (int r = 0; r < 4; ++r)
                #pragma unroll
                for (int c = 0; c < 8; ++c) acc[r][c] += a[r] * bv[c];
        }
        #pragma unroll
        for (int r = 0; r < 4; ++r) {
            size_t ro = ((size_t)bh * TK + rh * 64 + ty * 4 + r) * 512 + ct * 128;
            #pragma unroll
            for (int cc = 0; cc < 4; ++cc) {
                deltaout[ro + tx * 4 + cc]      = acc[r][cc];
                deltaout[ro + 64 + tx * 4 + cc] = acc[r][4 + cc];
            }
        }
    } else {
        int r2 = bid - 512;
        int b = r2 >> 3;
        int c0 = (r2 & 7) * 64;
        int c = tid & 63, kg = tid >> 6;
        float s = 0.f;
        #pragma unroll 8
        for (int k = kg * 128; k < kg * 128 + 128; ++k) {
            float hu = sv[(b * 8 + (k >> 6)) * 64 + (k & 63)] * (1.0f / Nseq);
            s += hu * w_out[(size_t)k * 512 + c0 + c];
        }
        __shared__ float red[4][64];
        red[kg][c] = s;
        __syncthreads();
        if (tid < 64)
            ubase[b * 512 + c0 + c] = red[0][c] + red[1][c] + red[2][c] + red[3][c] + b_out[c0 + c];
    }
}

// ---------------------------------------------------------------
// compose2: rankmap preloaded into registers before gathers.
// ---------------------------------------------------------------
__global__ __launch_bounds__(256) void compose2(const float* __restrict__ ubase,
                                                const int* __restrict__ rankmap,
                                                const float* __restrict__ deltaout,
                                                float* __restrict__ out) {
    int r0 = blockIdx.x * 4;
    int b = r0 >> 11;
    int tid = threadIdx.x;
    float u0 = ubase[b * 512 + tid];
    float u1 = ubase[b * 512 + 256 + tid];
    for (int rr = 0; rr < 4; ++rr) {
        int i = (r0 + rr) & 2047;
        int rk[8];
        #pragma unroll
        for (int h = 0; h < 8; ++h)
            rk[h] = rankmap[(size_t)(b * 8 + h) * Nseq + i];
        float a0 = u0, a1 = u1;
        #pragma unroll
        for (int h = 0; h < 8; ++h) {
            if (rk[h] >= 0) {
                const float* dp = deltaout + ((size_t)(b * 8 + h) * TK + rk[h]) * 512;
                a0 += dp[tid];
                a1 += dp[256 + tid];
            }
        }
        float* op = out + ((size_t)b * Nseq + i) * 512;
        op[tid] = a0;
        op[256 + tid] = a1;
    }
}

extern "C" void kernel_launch(void* const* d_in, const int* in_sizes, int n_in,
                              void* d_out, int out_size, void* d_ws, size_t ws_size,
                              hipStream_t stream) {
    const float* x     = (const float*)d_in[0];
    const float* w_qkv = (const float*)d_in[1];
    const float* w_out = (const float*)d_in[2];
    const float* b_out = (const float*)d_in[3];
    float* out = (float*)d_out;

    float* ws = (float*)d_ws;
    float* spart   = ws;                            // 98304 f
    float* sv      = spart + 98304;                 // 2048 f
    float* rvec    = sv + 2048;                     // 16384 f
    float* cvec    = rvec + 16384;
    float* rsc     = cvec + 16384;                  // 65536 f
    float* csc     = rsc + 65536;
    int*   ridx    = (int*)(csc + 65536);           // 8192 i
    int*   cidx    = ridx + 8192;
    int*   rankmap = cidx + 8192;                   // 65536 i
    float* ubase   = (float*)(rankmap + 65536);     // 2048 f
    bf16x8* Bp_hi  = (bf16x8*)(ubase + 2048);       // 393216 f
    bf16x8* Bp_lo  = (bf16x8*)((float*)Bp_hi + 393216);
    float* qsel    = (float*)Bp_lo + 393216;        // 524288 f
    float* ksel    = qsel + 524288;
    float* vsel    = ksel + 524288;
    float* delta   = vsel + 524288;                 // 524288 f
    float* deltaout = delta + 524288;               // 4194304 f

    // 1. stats GEMM direct-from-x (xprep folded in) + W fragment packing
    statsAW<<<768, 256, 0, stream>>>(x, w_qkv, spart, Bp_hi, Bp_lo);
    // 2. finalize qm/km/sv + folded score vectors
    statsB<<<dim3(BH, 2), 256, 0, stream>>>(spart, w_qkv, sv, rvec, cvec);
    // 3. rank-1 scores, single pass over x
    score4_kernel<<<dim3(Bsz, 128), 128, 0, stream>>>(x, rvec, cvec, rsc, csc);
    // 4. top-256 + rankmap via radix-select
    topk6<<<BH * 2, 256, 0, stream>>>(rsc, csc, ridx, cidx, rankmap);
    // 5. barrier-free gather-GEMM (B prefetch)
    selgemm4<<<dim3(4, 3, BH), 256, 0, stream>>>(x, ridx, cidx, Bp_hi, Bp_lo, qsel, ksel, vsel);
    // 6. fused attention (deep-ILP QK+PV) -> compact delta
    attn_fused4<<<dim3(BH, 16), 256, 0, stream>>>(qsel, ksel, vsel, sv, delta);
    // 7. delta @ w_out (register-staged LDS fills) + uniform base rows
    deltamm_ub<<<544, 256, 0, stream>>>(delta, w_out, b_out, sv, deltaout, ubase);
    // 8. compose final output
    compose2<<<Bsz * Nseq / 4, 256, 0, stream>>>(ubase, rankmap, deltaout, out);
}